// Round 1
// baseline (2231.881 us; speedup 1.0000x reference)
//
#include <hip/hip_runtime.h>
#include <hip/hip_bf16.h>

typedef __bf16 bf16_t;
typedef __bf16 bf16x8 __attribute__((ext_vector_type(8)));
typedef __bf16 bf16x4 __attribute__((ext_vector_type(4)));
typedef float  f32x4  __attribute__((ext_vector_type(4)));

#define BM 128
#define BN 128
#define BK 32

// ---------------- cast + transpose H: H[b,d,l] f32 -> Hb (same layout, bf16)
// and HTb[b,l,d] bf16 ----------------
__global__ __launch_bounds__(256) void cast_transpose_H(
    const float* __restrict__ H, bf16_t* __restrict__ Hb,
    bf16_t* __restrict__ HTb, int D, int L) {
  __shared__ bf16_t tile[32][33];
  int b = blockIdx.z;
  int l0 = blockIdx.x * 32, d0 = blockIdx.y * 32;
  const float* Hp = H + (size_t)b * D * L;
  bf16_t* Hbp = Hb + (size_t)b * D * L;
  bf16_t* HTp = HTb + (size_t)b * L * D;
  int tx = threadIdx.x, ty = threadIdx.y;
#pragma unroll
  for (int r = 0; r < 4; r++) {
    int d = d0 + ty + r * 8;
    float v = Hp[(size_t)d * L + l0 + tx];
    bf16_t bv = (bf16_t)v;
    tile[ty + r * 8][tx] = bv;
    Hbp[(size_t)d * L + l0 + tx] = bv;
  }
  __syncthreads();
#pragma unroll
  for (int r = 0; r < 4; r++) {
    int l = l0 + ty + r * 8;
    HTp[(size_t)l * D + d0 + tx] = tile[tx][ty + r * 8];
  }
}

// ---------------- simple casts ----------------
__global__ void cast_w(const float* __restrict__ in, bf16_t* __restrict__ out, int n) {
  int i = blockIdx.x * 256 + threadIdx.x;
  if (i < n) out[i] = (bf16_t)in[i];
}

// cast with padded output row stride (for 16B-aligned rows)
__global__ void cast_w_pad(const float* __restrict__ in, bf16_t* __restrict__ out,
                           int cols, int ldo) {
  int c = blockIdx.x * 256 + threadIdx.x;
  int r = blockIdx.y;
  if (c < cols) out[(size_t)r * ldo + c] = (bf16_t)in[(size_t)r * cols + c];
}

// ---------------- staging load helpers ----------------
__device__ inline bf16x8 cvt8(float4 a, float4 b) {
  bf16x8 o;
  o[0] = (bf16_t)a.x; o[1] = (bf16_t)a.y; o[2] = (bf16_t)a.z; o[3] = (bf16_t)a.w;
  o[4] = (bf16_t)b.x; o[5] = (bf16_t)b.y; o[6] = (bf16_t)b.z; o[7] = (bf16_t)b.w;
  return o;
}
__device__ inline bf16x8 load8v(const bf16_t* p) { return *(const bf16x8*)p; }
__device__ inline bf16x8 load8v(const float* p) {
  const float4* q4 = (const float4*)p;
  float4 a = q4[0], b = q4[1];
  return cvt8(a, b);
}
__device__ inline float loadS(const bf16_t* p) { return (float)*p; }
__device__ inline float loadS(const float* p) { return *p; }

// ---------------- GEMM: C[m][n] = sum_k A[m][k] * BT[n][k] ----------------
// A: M x K (row stride lda), source dtype AT (bf16 or f32, converted to bf16)
// BT: N x K bf16 (row stride ldb). N and n-tiling assumed multiple of 128.
// EPI 0: C fp32 [m][n] (row stride ldc)
// EPI 1: C bf16 stored TRANSPOSED: Ct[n][m] (row stride ldc)
// EPI 2: C bf16 [m][n] = acc * W[m][n]  (W fp32, row stride N)
template <typename AT, int EPI>
__global__ __launch_bounds__(256) void gemm_bt(
    const AT* __restrict__ A, long sAb, const bf16_t* __restrict__ BT, long sBb,
    void* __restrict__ Cv, long sCb, const float* __restrict__ W,
    int M, int N, int K, int lda, int ldb, int ldc) {
  __shared__ __align__(16) bf16_t As[4][BM][8];
  __shared__ __align__(16) bf16_t Bs[4][BN][8];
  int b = blockIdx.z;
  A += (size_t)b * sAb;
  BT += (size_t)b * sBb;
  int m0 = blockIdx.x * BM, n0 = blockIdx.y * BN;
  int t = threadIdx.x;
  int lane = t & 63;
  int wid = t >> 6;
  int l15 = lane & 15, q = lane >> 4;
  int wm = (wid >> 1) * 64, wn = (wid & 1) * 64;

  f32x4 acc[4][4];
#pragma unroll
  for (int i = 0; i < 4; i++)
#pragma unroll
    for (int j = 0; j < 4; j++)
#pragma unroll
      for (int e = 0; e < 4; e++) acc[i][j][e] = 0.0f;

  for (int kb = 0; kb < K; kb += BK) {
    __syncthreads();
    // stage A tile: 128 rows x 4 chunks of 8 (K-contiguous)
#pragma unroll
    for (int p0 = 0; p0 < 512; p0 += 256) {
      int p = p0 + t;
      int row = p >> 2, ch = p & 3;
      int gm = m0 + row, gk = kb + ch * 8;
      bf16x8 v;
      if (gm < M && gk + 8 <= K) {
        v = load8v(A + (size_t)gm * lda + gk);
      } else {
#pragma unroll
        for (int i = 0; i < 8; i++) {
          float x = 0.0f;
          if (gm < M && gk + i < K) x = loadS(A + (size_t)gm * lda + gk + i);
          v[i] = (bf16_t)x;
        }
      }
      *(bf16x8*)(&As[ch][row][0]) = v;
    }
    // stage BT tile (N rows always in-bounds: N % 128 == 0)
#pragma unroll
    for (int p0 = 0; p0 < 512; p0 += 256) {
      int p = p0 + t;
      int row = p >> 2, ch = p & 3;
      int gn = n0 + row, gk = kb + ch * 8;
      bf16x8 v;
      if (gk + 8 <= K) {
        v = load8v(BT + (size_t)gn * ldb + gk);
      } else {
#pragma unroll
        for (int i = 0; i < 8; i++) {
          float x = 0.0f;
          if (gk + i < K) x = (float)BT[(size_t)gn * ldb + gk + i];
          v[i] = (bf16_t)x;
        }
      }
      *(bf16x8*)(&Bs[ch][row][0]) = v;
    }
    __syncthreads();

    bf16x8 af[4], bfr[4];
#pragma unroll
    for (int i = 0; i < 4; i++) af[i] = *(const bf16x8*)(&As[q][wm + i * 16 + l15][0]);
#pragma unroll
    for (int j = 0; j < 4; j++) bfr[j] = *(const bf16x8*)(&Bs[q][wn + j * 16 + l15][0]);
#pragma unroll
    for (int i = 0; i < 4; i++)
#pragma unroll
      for (int j = 0; j < 4; j++)
        acc[i][j] = __builtin_amdgcn_mfma_f32_16x16x32_bf16(af[i], bfr[j], acc[i][j], 0, 0, 0);
  }

  // epilogue: C/D layout col = lane&15, row = (lane>>4)*4 + reg
#pragma unroll
  for (int i = 0; i < 4; i++) {
    int rbase = m0 + wm + i * 16 + q * 4;
#pragma unroll
    for (int j = 0; j < 4; j++) {
      int c = n0 + wn + j * 16 + l15;
#pragma unroll
      for (int r4 = 0; r4 < 4; r4++) {
        int r = rbase + r4;
        if (r < M) {
          float val = acc[i][j][r4];
          if (EPI == 0) {
            float* Cp = (float*)Cv + (size_t)b * sCb;
            Cp[(size_t)r * ldc + c] = val;
          } else if (EPI == 1) {
            bf16_t* Cp = (bf16_t*)Cv + (size_t)b * sCb;
            Cp[(size_t)c * ldc + r] = (bf16_t)val;
          } else {
            float w = W[(size_t)r * N + c];
            bf16_t* Cp = (bf16_t*)Cv + (size_t)b * sCb;
            Cp[(size_t)r * ldc + c] = (bf16_t)(val * w);
          }
        }
      }
    }
  }
}

// ---------------- row softmax, L = 4096 (16 elems/thread, 256 threads) -----
// OUT_BF16: 1 -> write bf16 to out; 0 -> write fp32 to out (may alias in)
template <int OUT_BF16>
__global__ __launch_bounds__(256) void softmax_rows(
    const float* __restrict__ in, void* __restrict__ out, int L) {
  int row = blockIdx.x;
  const float* ip = in + (size_t)row * L;
  int t = threadIdx.x;
  int lane = t & 63, wid = t >> 6;
  float4 v[4];
  float m = -3.4e38f;
#pragma unroll
  for (int c = 0; c < 4; c++) {
    v[c] = ((const float4*)ip)[c * 256 + t];
    m = fmaxf(m, fmaxf(fmaxf(v[c].x, v[c].y), fmaxf(v[c].z, v[c].w)));
  }
#pragma unroll
  for (int off = 1; off < 64; off <<= 1) m = fmaxf(m, __shfl_xor(m, off));
  __shared__ float redm[4];
  __shared__ float reds[4];
  if (lane == 0) redm[wid] = m;
  __syncthreads();
  m = fmaxf(fmaxf(redm[0], redm[1]), fmaxf(redm[2], redm[3]));
  float s = 0.0f;
#pragma unroll
  for (int c = 0; c < 4; c++) {
    v[c].x = __expf(v[c].x - m);
    v[c].y = __expf(v[c].y - m);
    v[c].z = __expf(v[c].z - m);
    v[c].w = __expf(v[c].w - m);
    s += (v[c].x + v[c].y) + (v[c].z + v[c].w);
  }
#pragma unroll
  for (int off = 1; off < 64; off <<= 1) s += __shfl_xor(s, off);
  if (lane == 0) reds[wid] = s;
  __syncthreads();
  s = (reds[0] + reds[1]) + (reds[2] + reds[3]);
  float inv = 1.0f / s;
  if (OUT_BF16) {
    bf16_t* op = (bf16_t*)out + (size_t)row * L;
#pragma unroll
    for (int c = 0; c < 4; c++) {
      bf16x4 o;
      o[0] = (bf16_t)(v[c].x * inv);
      o[1] = (bf16_t)(v[c].y * inv);
      o[2] = (bf16_t)(v[c].z * inv);
      o[3] = (bf16_t)(v[c].w * inv);
      *(bf16x4*)(op + ((size_t)c * 256 + t) * 4) = o;
    }
  } else {
    float* op = (float*)out + (size_t)row * L;
#pragma unroll
    for (int c = 0; c < 4; c++) {
      float4 o = make_float4(v[c].x * inv, v[c].y * inv, v[c].z * inv, v[c].w * inv);
      ((float4*)op)[c * 256 + t] = o;
    }
  }
}

extern "C" void kernel_launch(void* const* d_in, const int* in_sizes, int n_in,
                              void* d_out, int out_size, void* d_ws, size_t ws_size,
                              hipStream_t stream) {
  const int B = 4, D = 512, L = 4096, N1 = 1167, N2 = 8921;
  const int N1P = 1168;  // padded row stride for K=N1 operands (16B-aligned rows)
  const float* H = (const float*)d_in[0];
  const float* Q1w = (const float*)d_in[1];
  const float* Q2w = (const float*)d_in[2];
  const float* Q12w = (const float*)d_in[3];
  float* C2 = (float*)d_out;                  // [B, N2, D] fp32
  float* A2 = C2 + (size_t)B * N2 * D;        // [B, N2, L] fp32 (E2 in place)

  char* ws = (char*)d_ws;
  size_t off = 0;
  auto alloc = [&](size_t bytes) -> void* {
    void* p = ws + off;
    off = (off + bytes + 255) & ~(size_t)255;
    return p;
  };
  bf16_t* Hb   = (bf16_t*)alloc((size_t)B * D * L * 2);
  bf16_t* HTb  = (bf16_t*)alloc((size_t)B * L * D * 2);
  bf16_t* Q1b  = (bf16_t*)alloc((size_t)N1 * D * 2);
  bf16_t* Q12b = (bf16_t*)alloc((size_t)N2 * N1P * 2);
  float*  E1   = (float*)alloc((size_t)B * N1 * L * 4);
  bf16_t* A1b  = (bf16_t*)alloc((size_t)B * N1 * L * 2);
  bf16_t* C1Tb = (bf16_t*)alloc((size_t)B * D * N1P * 2);
  bf16_t* Q2b  = (bf16_t*)alloc((size_t)B * N2 * D * 2);
  (void)ws_size;

  // 1. bf16 cast of H + transpose
  cast_transpose_H<<<dim3(L / 32, D / 32, B), dim3(32, 8), 0, stream>>>(H, Hb, HTb, D, L);
  // 2. weight casts
  cast_w<<<(N1 * D + 255) / 256, 256, 0, stream>>>(Q1w, Q1b, N1 * D);
  cast_w_pad<<<dim3((N1 + 255) / 256, N2), 256, 0, stream>>>(Q12w, Q12b, N1, N1P);
  // 3. E1[b] = Q1 @ H[b]   (M=N1, N=L, K=D; BT = HT)
  gemm_bt<bf16_t, 0><<<dim3((N1 + BM - 1) / BM, L / BN, B), 256, 0, stream>>>(
      Q1b, 0, HTb, (long)L * D, E1, (long)N1 * L, nullptr, N1, L, D, D, D, L);
  // 4. A1 = softmax(E1) -> bf16
  softmax_rows<1><<<B * N1, 256, 0, stream>>>(E1, A1b, L);
  // 5. C1T[b] = (A1 @ H^T)^T stored as [D][N1P] bf16  (M=N1, N=D, K=L; BT = H)
  gemm_bt<bf16_t, 1><<<dim3((N1 + BM - 1) / BM, D / BN, B), 256, 0, stream>>>(
      A1b, (long)N1 * L, Hb, (long)D * L, C1Tb, (long)D * N1P, nullptr, N1, D, L, L, L, N1P);
  // 6. Q2[b] = (Q12 @ C1) * Q2w -> bf16  (M=N2, N=D, K=N1; BT = C1T)
  gemm_bt<bf16_t, 2><<<dim3((N2 + BM - 1) / BM, D / BN, B), 256, 0, stream>>>(
      Q12b, 0, C1Tb, (long)D * N1P, Q2b, (long)N2 * D, Q2w, N2, D, N1, N1P, N1P, D);
  // 7. E2[b] = Q2 @ H[b] -> fp32 into A2 region  (M=N2, N=L, K=D; BT = HT)
  gemm_bt<bf16_t, 0><<<dim3((N2 + BM - 1) / BM, L / BN, B), 256, 0, stream>>>(
      Q2b, (long)N2 * D, HTb, (long)L * D, A2, (long)N2 * L, nullptr, N2, L, D, D, D, L);
  // 8. A2 = softmax(E2) in place (fp32)
  softmax_rows<0><<<B * N2, 256, 0, stream>>>(A2, A2, L);
  // 9. C2[b] = A2 @ H[b]^T  (M=N2, N=D, K=L; A is fp32, BT = H)
  gemm_bt<float, 0><<<dim3((N2 + BM - 1) / BM, D / BN, B), 256, 0, stream>>>(
      A2, (long)N2 * L, Hb, (long)D * L, C2, (long)N2 * D, nullptr, N2, D, L, L, L, D);
}